// Round 1
// baseline (10695.791 us; speedup 1.0000x reference)
//
#include <hip/hip_runtime.h>
#include <hip/hip_bf16.h>
#include <math.h>

// Problem constants
constexpr int B_ = 2, T_ = 2048, C_ = 1024, NH_ = 16, HS_ = 64, BD_ = 16, DELTA_ = 32;
constexpr int M_ = B_ * T_;   // 4096 rows

__device__ __forceinline__ float gelu_f(float v) {
    return 0.5f * v * (1.0f + erff(v * 0.70710678118654752f));
}

// ---------------------------------------------------------------------------
// Generic tiled fp32 GEMM: C[M,N] = A[M,K] @ W[K,N] + bias[N]
// 64x64 tile, 16x16 threads, each thread 4x4, K-tile 16.
// M % 64 == 0, N % 64 == 0, K % 16 == 0 (true for all our shapes).
// ---------------------------------------------------------------------------
#define GTS 64
#define GKT 16
__global__ __launch_bounds__(256) void gemm_bias_kernel(
    const float* __restrict__ A, const float* __restrict__ W,
    const float* __restrict__ bias, float* __restrict__ C,
    int M, int N, int K)
{
    __shared__ float As[GKT][GTS + 1];
    __shared__ float Ws[GKT][GTS + 1];
    const int bm = blockIdx.y * GTS;
    const int bn = blockIdx.x * GTS;
    const int tx = threadIdx.x;     // 0..15
    const int ty = threadIdx.y;     // 0..15
    const int tid = ty * 16 + tx;

    float acc[4][4] = {};

    for (int k0 = 0; k0 < K; k0 += GKT) {
        // Load A tile: 64 rows x 16 k. 256 threads * 4 floats.
        {
            const int row = tid >> 2;          // 0..63
            const int kk  = (tid & 3) * 4;     // 0,4,8,12
            const float4 v = *(const float4*)(A + (size_t)(bm + row) * K + k0 + kk);
            As[kk + 0][row] = v.x; As[kk + 1][row] = v.y;
            As[kk + 2][row] = v.z; As[kk + 3][row] = v.w;
        }
        // Load W tile: 16 k x 64 n. 256 threads * 4 floats.
        {
            const int kk  = tid >> 4;          // 0..15
            const int col = (tid & 15) * 4;    // 0..60
            const float4 v = *(const float4*)(W + (size_t)(k0 + kk) * N + bn + col);
            Ws[kk][col + 0] = v.x; Ws[kk][col + 1] = v.y;
            Ws[kk][col + 2] = v.z; Ws[kk][col + 3] = v.w;
        }
        __syncthreads();
        #pragma unroll
        for (int kk = 0; kk < GKT; ++kk) {
            float a[4], w[4];
            #pragma unroll
            for (int i = 0; i < 4; ++i) a[i] = As[kk][ty * 4 + i];
            #pragma unroll
            for (int j = 0; j < 4; ++j) w[j] = Ws[kk][tx * 4 + j];
            #pragma unroll
            for (int i = 0; i < 4; ++i)
                #pragma unroll
                for (int j = 0; j < 4; ++j)
                    acc[i][j] += a[i] * w[j];
        }
        __syncthreads();
    }

    #pragma unroll
    for (int i = 0; i < 4; ++i) {
        const int r = bm + ty * 4 + i;
        #pragma unroll
        for (int j = 0; j < 4; ++j) {
            const int c = bn + tx * 4 + j;
            C[(size_t)r * N + c] = acc[i][j] + bias[c];
        }
    }
}

// ---------------------------------------------------------------------------
// State kernel: state[b,t,h*16+e] = (mean_valid(disp window) - disp_t) @ w_state + b_state
// One block per (b,t); 16x16 threads = (h, e).
// ---------------------------------------------------------------------------
__global__ __launch_bounds__(256) void state_kernel(
    const float* __restrict__ disp,     // [B*T, 256]
    const float* __restrict__ w_state,  // [16,16] row-major
    const float* __restrict__ b_state,  // [16]
    float* __restrict__ state)          // [B*T, 256]
{
    const int bt = blockIdx.x;          // 0..M_-1
    const int t  = bt & (T_ - 1);
    const int e  = threadIdx.x;         // 0..15
    const int h  = threadIdx.y;         // 0..15
    const int tid = h * 16 + e;

    __shared__ float mv[16][17];
    __shared__ float ws[16][16];
    ws[tid >> 4][tid & 15] = w_state[tid];

    const int dlo = max(0, 31 - t);
    const float cnt = (float)(32 - dlo);
    const float* dp = disp + (size_t)bt * 256 + h * 16 + e;
    float s = 0.0f;
    for (int d = dlo; d < 32; ++d)
        s += dp[(ptrdiff_t)(d - 31) * 256];
    mv[h][e] = s / cnt - dp[0];
    __syncthreads();

    float acc = b_state[e];
    #pragma unroll
    for (int k = 0; k < 16; ++k)
        acc += mv[h][k] * ws[k][e];
    state[(size_t)bt * 256 + h * 16 + e] = acc;
}

// ---------------------------------------------------------------------------
// Attention kernel: one wave (64 lanes) per (b,h,t).
//  - lane d in [0,32): bond+damage scoring for window slot d
//  - 32-lane shfl softmax
//  - all 64 lanes: out[e=lane] = sum_d w_d * val[t-31+d, h*64+e]
// Block = 512 threads = 8 waves.
// ---------------------------------------------------------------------------
#define ATT_WAVES 8
__global__ __launch_bounds__(512) void attn_kernel(
    const float* __restrict__ disp,     // [B*T, 256]
    const float* __restrict__ state,    // [B*T, 256]
    const float* __restrict__ val,      // [B*T, 1024]
    const float* __restrict__ rel_pos_emb, // [32,16]
    const float* __restrict__ w_strain, const float* __restrict__ b_strain,
    const float* __restrict__ w_state_i, const float* __restrict__ w_state_j,
    const float* __restrict__ w_pos,
    const float* __restrict__ w_bond_out, const float* __restrict__ b_bond_out,
    const float* __restrict__ w_damage, const float* __restrict__ b_damage,
    const float* __restrict__ w_damage_out, const float* __restrict__ b_damage_out,
    float* __restrict__ att)            // [B*T, 1024]
{
    __shared__ float s_wstr[16][16], s_wdmg[16][16], s_wsi[16][16], s_wsj[16][16];
    __shared__ float s_relw[32][16];
    __shared__ float s_bstr[16], s_bdmg[16], s_wbond[16], s_wdout[16];

    const int tid = threadIdx.x;
    if (tid < 256) {
        const int k = tid >> 4, e = tid & 15;
        s_wstr[k][e] = w_strain[tid];
        s_wdmg[k][e] = w_damage[tid];
        s_wsi[k][e]  = w_state_i[tid];
        s_wsj[k][e]  = w_state_j[tid];
        if (tid < 16) {
            s_bstr[tid]  = b_strain[tid];
            s_bdmg[tid]  = b_damage[tid];
            s_wbond[tid] = w_bond_out[tid];
            s_wdout[tid] = w_damage_out[tid];
        }
    }
    {   // relw[d][e] = sum_k rel_emb[d,k] * w_pos[k,e]; 512 entries, 512 threads
        const int d = tid >> 4, e = tid & 15;
        float a = 0.0f;
        #pragma unroll
        for (int k = 0; k < 16; ++k)
            a += rel_pos_emb[d * 16 + k] * w_pos[k * 16 + e];
        s_relw[d][e] = a;
    }
    __syncthreads();

    const int lane = tid & 63;
    const int widx = tid >> 6;
    const int g = blockIdx.x * ATT_WAVES + widx;   // 0..B*NH*T-1
    const int t  = g & (T_ - 1);
    const int bh = g >> 11;                        // g / T_
    const int h  = bh & (NH_ - 1);
    const int b  = bh >> 4;

    const float* dispbase  = disp  + (size_t)(b * T_ + t) * 256 + h * 16;
    const float* statebase = state + (size_t)(b * T_ + t) * 256 + h * 16;

    float disp_t[16], state_t[16], si[16];
    #pragma unroll
    for (int k = 0; k < 16; ++k) disp_t[k]  = dispbase[k];
    #pragma unroll
    for (int k = 0; k < 16; ++k) state_t[k] = statebase[k];
    #pragma unroll
    for (int e = 0; e < 16; ++e) {
        float a = 0.0f;
        #pragma unroll
        for (int k = 0; k < 16; ++k) a += state_t[k] * s_wsi[k][e];
        si[e] = a;
    }

    const int dlo = max(0, 31 - t);
    const int d = lane;
    float logit = -INFINITY;
    if (d >= dlo && d < 32) {
        const float* dp0 = dispbase  + (ptrdiff_t)(d - 31) * 256;
        const float* sp0 = statebase + (ptrdiff_t)(d - 31) * 256;
        float pre[16], pre2[16];
        #pragma unroll
        for (int e = 0; e < 16; ++e) {
            pre[e]  = s_bstr[e] + si[e] + s_relw[d][e];
            pre2[e] = s_bdmg[e];
        }
        #pragma unroll
        for (int k = 0; k < 16; ++k) {
            const float st = dp0[k] - disp_t[k];
            const float s0 = sp0[k];
            #pragma unroll
            for (int e = 0; e < 16; ++e) {
                pre[e]  += st * s_wstr[k][e] + s0 * s_wsj[k][e];
                pre2[e] += st * s_wdmg[k][e];
            }
        }
        float bacc = 0.0f, dacc = 0.0f;
        #pragma unroll
        for (int e = 0; e < 16; ++e) {
            bacc += gelu_f(pre[e])  * s_wbond[e];
            dacc += gelu_f(pre2[e]) * s_wdout[e];
        }
        const float bond_logit = bacc + b_bond_out[0];
        const float damage = 1.0f / (1.0f + expf(-(dacc + b_damage_out[0])));
        logit = bond_logit - 10.0f * damage;
    }

    // masked softmax over lanes 0..31
    float m = logit;
    #pragma unroll
    for (int off = 16; off; off >>= 1) m = fmaxf(m, __shfl_xor(m, off, 32));
    float p = (d >= dlo && d < 32) ? expf(logit - m) : 0.0f;
    float ssum = p;
    #pragma unroll
    for (int off = 16; off; off >>= 1) ssum += __shfl_xor(ssum, off, 32);
    const float wv = p / ssum;   // NaN on lanes>=32, never read

    // PV: out[e=lane] = sum_d w_d * val[t-31+d, h*64+lane]
    float acc = 0.0f;
    const float* valbase = val + (size_t)(b * T_ + t) * 1024 + h * 64 + lane;
    for (int dd = dlo; dd < 32; ++dd) {
        const float wd = __shfl(wv, dd, 64);
        acc += wd * valbase[(ptrdiff_t)(dd - 31) * 1024];
    }
    att[(size_t)(b * T_ + t) * 1024 + h * 64 + lane] = acc;
}

// ---------------------------------------------------------------------------
extern "C" void kernel_launch(void* const* d_in, const int* in_sizes, int n_in,
                              void* d_out, int out_size, void* d_ws, size_t ws_size,
                              hipStream_t stream)
{
    const float* x        = (const float*)d_in[0];
    const float* w_disp   = (const float*)d_in[1];
    const float* b_disp   = (const float*)d_in[2];
    const float* w_val    = (const float*)d_in[3];
    const float* b_val    = (const float*)d_in[4];
    const float* rel      = (const float*)d_in[5];
    const float* w_state  = (const float*)d_in[6];
    const float* b_state  = (const float*)d_in[7];
    const float* w_strain = (const float*)d_in[8];
    const float* b_strain = (const float*)d_in[9];
    const float* w_si     = (const float*)d_in[10];
    const float* w_sj     = (const float*)d_in[11];
    const float* w_pos    = (const float*)d_in[12];
    const float* w_bond   = (const float*)d_in[13];
    const float* b_bond   = (const float*)d_in[14];
    const float* w_dmg    = (const float*)d_in[15];
    const float* b_dmg    = (const float*)d_in[16];
    const float* w_dout   = (const float*)d_in[17];
    const float* b_dout   = (const float*)d_in[18];
    const float* w_cproj  = (const float*)d_in[19];
    const float* b_cproj  = (const float*)d_in[20];

    float* out = (float*)d_out;
    float* ws  = (float*)d_ws;

    // workspace layout (floats): disp[M*256] | state[M*256] | val[M*1024] | att[M*1024]
    float* disp  = ws;
    float* state = ws + (size_t)M_ * 256;
    float* val   = ws + (size_t)2 * M_ * 256;
    float* att   = ws + (size_t)2 * M_ * 256 + (size_t)M_ * 1024;

    dim3 blk(16, 16);
    // disp = x @ w_disp + b_disp   (M x 1024 x 256)
    gemm_bias_kernel<<<dim3(256 / GTS, M_ / GTS), blk, 0, stream>>>(x, w_disp, b_disp, disp, M_, 256, C_);
    // val = x @ w_val + b_val      (M x 1024 x 1024)
    gemm_bias_kernel<<<dim3(C_ / GTS, M_ / GTS), blk, 0, stream>>>(x, w_val, b_val, val, M_, C_, C_);
    // state
    state_kernel<<<M_, dim3(16, 16), 0, stream>>>(disp, w_state, b_state, state);
    // attention
    attn_kernel<<<(B_ * NH_ * T_) / ATT_WAVES, ATT_WAVES * 64, 0, stream>>>(
        disp, state, val, rel, w_strain, b_strain, w_si, w_sj, w_pos,
        w_bond, b_bond, w_dmg, b_dmg, w_dout, b_dout, att);
    // out = att @ w_cproj + b_cproj
    gemm_bias_kernel<<<dim3(C_ / GTS, M_ / GTS), blk, 0, stream>>>(att, w_cproj, b_cproj, out, M_, C_, C_);
}

// Round 3
// 317.539 us; speedup vs baseline: 33.6834x; 33.6834x over previous
//
#include <hip/hip_runtime.h>
#include <hip/hip_bf16.h>
#include <math.h>

// Problem constants
constexpr int B_ = 2, T_ = 2048, C_ = 1024, NH_ = 16, HS_ = 64, BD_ = 16, DELTA_ = 32;
constexpr int M_ = B_ * T_;   // 4096 rows

typedef __bf16 bf16_t;
typedef __bf16 bf16x8 __attribute__((ext_vector_type(8)));
typedef float  f32x4  __attribute__((ext_vector_type(4)));

__device__ __forceinline__ float gelu_f(float v) {
    return 0.5f * v * (1.0f + erff(v * 0.70710678118654752f));
}

// ---------------------------------------------------------------------------
// convert fp32 -> bf16 (n multiple of 2048)
// ---------------------------------------------------------------------------
__global__ __launch_bounds__(256) void convert_bf16_kernel(
    const float* __restrict__ in, bf16_t* __restrict__ out, int n)
{
    const int i = (blockIdx.x * 256 + threadIdx.x) * 8;
    if (i >= n) return;
    const float4 v0 = *(const float4*)(in + i);
    const float4 v1 = *(const float4*)(in + i + 4);
    bf16x8 o;
    o[0] = (bf16_t)v0.x; o[1] = (bf16_t)v0.y; o[2] = (bf16_t)v0.z; o[3] = (bf16_t)v0.w;
    o[4] = (bf16_t)v1.x; o[5] = (bf16_t)v1.y; o[6] = (bf16_t)v1.z; o[7] = (bf16_t)v1.w;
    *(bf16x8*)(out + i) = o;
}

// ---------------------------------------------------------------------------
// transpose + convert: in fp32 [K][N] -> out bf16 [N][K].  K,N multiples of 32.
// ---------------------------------------------------------------------------
__global__ __launch_bounds__(256) void transpose_w_kernel(
    const float* __restrict__ in, bf16_t* __restrict__ out, int K, int N)
{
    __shared__ float tile[32][33];
    const int n0 = blockIdx.x * 32, k0 = blockIdx.y * 32;
    const int tx = threadIdx.x & 31, ty = threadIdx.x >> 5;   // ty 0..7
    #pragma unroll
    for (int i = 0; i < 4; ++i)
        tile[ty + 8 * i][tx] = in[(size_t)(k0 + ty + 8 * i) * N + n0 + tx];
    __syncthreads();
    #pragma unroll
    for (int i = 0; i < 4; ++i)
        out[(size_t)(n0 + ty + 8 * i) * K + k0 + tx] = (bf16_t)tile[tx][ty + 8 * i];
}

// ---------------------------------------------------------------------------
// bf16 MFMA GEMM: C[M,N] = A[M,K](bf16 row-major) @ Bt[N,K](bf16)^T + bias
// 128x128 tile, 4 waves (2x2), per-wave 64x64 = 4x4 fragments of 16x16x32.
// ---------------------------------------------------------------------------
#define BM 128
#define BN 128
#define BK 32
#define LDA 40   // BK + 8 pad  -> 80B row stride, 2-way max bank aliasing
__global__ __launch_bounds__(256) void gemm_bf16_kernel(
    const bf16_t* __restrict__ A, const bf16_t* __restrict__ Bt,
    const float* __restrict__ bias, float* __restrict__ C,
    int M, int N, int K)
{
    __shared__ bf16_t Al[BM][LDA];
    __shared__ bf16_t Bl[BN][LDA];
    const int tid  = threadIdx.x;
    const int lane = tid & 63;
    const int w    = tid >> 6;
    const int wr   = w >> 1, wc = w & 1;
    const int bm   = blockIdx.y * BM, bn = blockIdx.x * BN;

    const int srow = tid >> 1;           // 0..127
    const int scol = (tid & 1) * 16;     // 0 or 16

    f32x4 acc[4][4] = {};

    const bf16_t* Arow = A  + (size_t)(bm + srow) * K + scol;
    const bf16_t* Brow = Bt + (size_t)(bn + srow) * K + scol;

    for (int k0 = 0; k0 < K; k0 += BK) {
        const bf16x8 a0 = *(const bf16x8*)(Arow + k0);
        const bf16x8 a1 = *(const bf16x8*)(Arow + k0 + 8);
        const bf16x8 b0 = *(const bf16x8*)(Brow + k0);
        const bf16x8 b1 = *(const bf16x8*)(Brow + k0 + 8);
        __syncthreads();   // previous iteration's frag reads done
        *(bf16x8*)&Al[srow][scol]     = a0;
        *(bf16x8*)&Al[srow][scol + 8] = a1;
        *(bf16x8*)&Bl[srow][scol]     = b0;
        *(bf16x8*)&Bl[srow][scol + 8] = b1;
        __syncthreads();
        bf16x8 af[4], bfr[4];
        #pragma unroll
        for (int i = 0; i < 4; ++i)
            af[i] = *(const bf16x8*)&Al[wr * 64 + i * 16 + (lane & 15)][(lane >> 4) * 8];
        #pragma unroll
        for (int j = 0; j < 4; ++j)
            bfr[j] = *(const bf16x8*)&Bl[wc * 64 + j * 16 + (lane & 15)][(lane >> 4) * 8];
        #pragma unroll
        for (int i = 0; i < 4; ++i)
            #pragma unroll
            for (int j = 0; j < 4; ++j)
                acc[i][j] = __builtin_amdgcn_mfma_f32_16x16x32_bf16(af[i], bfr[j], acc[i][j], 0, 0, 0);
    }

    #pragma unroll
    for (int i = 0; i < 4; ++i) {
        const int r0 = bm + wr * 64 + i * 16 + (lane >> 4) * 4;
        #pragma unroll
        for (int j = 0; j < 4; ++j) {
            const int c = bn + wc * 64 + j * 16 + (lane & 15);
            const float bv = bias[c];
            float* cp = C + (size_t)r0 * N + c;
            #pragma unroll
            for (int q = 0; q < 4; ++q)
                cp[(size_t)q * N] = acc[i][j][q] + bv;
        }
    }
}

// ---------------------------------------------------------------------------
// Precompute kernel: per row r = (b,t), per head h (fp32):
//   state = (mean_valid(disp win) - disp[r]) @ w_state + b_state
//   P1[r] = disp[r]@w_strain + state@w_state_j
//   Q1[r] = b_strain + state@w_state_i - disp[r]@w_strain
//   P2[r] = disp[r]@w_damage
// ---------------------------------------------------------------------------
__global__ __launch_bounds__(256) void precomp_kernel(
    const float* __restrict__ disp,      // [M_, 256]
    const float* __restrict__ w_state, const float* __restrict__ b_state,
    const float* __restrict__ w_strain, const float* __restrict__ b_strain,
    const float* __restrict__ w_state_i, const float* __restrict__ w_state_j,
    const float* __restrict__ w_damage,
    float* __restrict__ P1, float* __restrict__ Q1, float* __restrict__ P2)
{
    const int bt  = blockIdx.x;
    const int t   = bt & (T_ - 1);
    const int tid = threadIdx.x;
    const int h   = tid >> 4;
    const int e   = tid & 15;

    __shared__ float s_wst[16][16], s_wstr[16][16], s_wsi[16][16], s_wsj[16][16], s_wdmg[16][16];
    __shared__ float s_dt[16][17], s_mv[16][17], s_st[16][17];

    s_wst[h][e]  = w_state[tid];
    s_wstr[h][e] = w_strain[tid];
    s_wsi[h][e]  = w_state_i[tid];
    s_wsj[h][e]  = w_state_j[tid];
    s_wdmg[h][e] = w_damage[tid];

    const float* dp = disp + (size_t)bt * 256 + tid;
    const int dlo = max(0, 31 - t);
    float s = 0.0f;
    for (int d = dlo; d < 32; ++d)
        s += dp[(ptrdiff_t)(d - 31) * 256];
    const float dt = dp[0];
    s_dt[h][e] = dt;
    s_mv[h][e] = s / (float)(32 - dlo) - dt;
    __syncthreads();

    float st_acc = b_state[e];
    #pragma unroll
    for (int k = 0; k < 16; ++k)
        st_acc += s_mv[h][k] * s_wst[k][e];
    s_st[h][e] = st_acc;
    __syncthreads();

    float d1 = 0.0f, p2 = 0.0f, sj = 0.0f, si = 0.0f;
    #pragma unroll
    for (int k = 0; k < 16; ++k) {
        const float dv = s_dt[h][k];
        const float sv = s_st[h][k];
        d1 += dv * s_wstr[k][e];
        p2 += dv * s_wdmg[k][e];
        sj += sv * s_wsj[k][e];
        si += sv * s_wsi[k][e];
    }
    const size_t o = (size_t)bt * 256 + tid;
    P1[o] = d1 + sj;
    Q1[o] = b_strain[e] + si - d1;
    P2[o] = p2;
}

// ---------------------------------------------------------------------------
// Attention kernel: one wave per pair of adjacent t. Scoring from P1/Q1/P2
// (no matmuls), 32-lane softmax per half, merged 33-row PV loop.
// Writes att as bf16.
// ---------------------------------------------------------------------------
#define AW 4
__global__ __launch_bounds__(256) void attn_kernel(
    const float* __restrict__ P1, const float* __restrict__ Q1,
    const float* __restrict__ P2, const float* __restrict__ val,
    const float* __restrict__ rel_pos_emb, const float* __restrict__ w_pos,
    const float* __restrict__ w_bond_out, const float* __restrict__ b_bond_out,
    const float* __restrict__ b_damage,
    const float* __restrict__ w_damage_out, const float* __restrict__ b_damage_out,
    bf16_t* __restrict__ att)            // [M_, 1024] bf16
{
    __shared__ float s_relw[32][20];
    __shared__ float s_wb[16], s_wd[16], s_bd[16];

    const int tid = threadIdx.x;
    #pragma unroll
    for (int i = 0; i < 2; ++i) {
        const int idx = tid + i * 256;
        const int dd = idx >> 4, ee = idx & 15;
        float a = 0.0f;
        #pragma unroll
        for (int k = 0; k < 16; ++k)
            a += rel_pos_emb[dd * 16 + k] * w_pos[k * 16 + ee];
        s_relw[dd][ee] = a;
    }
    if (tid < 16) {
        s_wb[tid] = w_bond_out[tid];
        s_wd[tid] = w_damage_out[tid];
        s_bd[tid] = b_damage[tid];
    }
    __syncthreads();

    const int lane = tid & 63;
    const int g2   = blockIdx.x * AW + (tid >> 6);
    const int t0   = (g2 & (T_ / 2 - 1)) * 2;
    const int bh   = g2 >> 10;
    const int h    = bh & (NH_ - 1);
    const int b    = bh >> 4;
    const int half = lane >> 5;
    const int d    = lane & 31;
    const int t    = t0 + half;
    const int rowd = t - 31 + d;
    const bool valid = (rowd >= 0);
    const int rowc = valid ? rowd : 0;

    const size_t tbase = (size_t)(b * T_ + t) * 256 + h * 16;
    const size_t rbase = (size_t)(b * T_ + rowc) * 256 + h * 16;

    const float4* Q1t4 = (const float4*)(Q1 + tbase);
    const float4* P2t4 = (const float4*)(P2 + tbase);
    const float4* P1r4 = (const float4*)(P1 + rbase);
    const float4* P2r4 = (const float4*)(P2 + rbase);

    float bacc = 0.0f, dacc = 0.0f;
    #pragma unroll
    for (int q = 0; q < 4; ++q) {
        const float4 p1  = P1r4[q];
        const float4 q1  = Q1t4[q];
        const float4 p2  = P2r4[q];
        const float4 p2t = P2t4[q];
        bacc += gelu_f(p1.x + q1.x + s_relw[d][4*q+0]) * s_wb[4*q+0];
        bacc += gelu_f(p1.y + q1.y + s_relw[d][4*q+1]) * s_wb[4*q+1];
        bacc += gelu_f(p1.z + q1.z + s_relw[d][4*q+2]) * s_wb[4*q+2];
        bacc += gelu_f(p1.w + q1.w + s_relw[d][4*q+3]) * s_wb[4*q+3];
        dacc += gelu_f(p2.x - p2t.x + s_bd[4*q+0]) * s_wd[4*q+0];
        dacc += gelu_f(p2.y - p2t.y + s_bd[4*q+1]) * s_wd[4*q+1];
        dacc += gelu_f(p2.z - p2t.z + s_bd[4*q+2]) * s_wd[4*q+2];
        dacc += gelu_f(p2.w - p2t.w + s_bd[4*q+3]) * s_wd[4*q+3];
    }

    float logit = -INFINITY;
    if (valid) {
        const float damage = 1.0f / (1.0f + expf(-(dacc + b_damage_out[0])));
        logit = bacc + b_bond_out[0] - 10.0f * damage;
    }

    float m = logit;
    #pragma unroll
    for (int off = 16; off; off >>= 1) m = fmaxf(m, __shfl_xor(m, off, 32));
    float p = valid ? expf(logit - m) : 0.0f;
    float ssum = p;
    #pragma unroll
    for (int off = 16; off; off >>= 1) ssum += __shfl_xor(ssum, off, 32);
    const float wv = p / ssum;

    float acc0 = 0.0f, acc1 = 0.0f;
    const float* vb = val + (size_t)(b * T_ + t0) * 1024 + h * 64 + lane;
    #pragma unroll
    for (int j = 0; j < 33; ++j) {
        const int row = t0 - 31 + j;
        float v = 0.0f;
        if (row >= 0) v = vb[(ptrdiff_t)(j - 31) * 1024];
        if (j < 32) acc0 += __shfl(wv, j, 64) * v;
        if (j >= 1) acc1 += __shfl(wv, 32 + j - 1, 64) * v;
    }
    att[(size_t)(b * T_ + t0) * 1024 + h * 64 + lane]     = (bf16_t)acc0;
    att[(size_t)(b * T_ + t0 + 1) * 1024 + h * 64 + lane] = (bf16_t)acc1;
}

// ---------------------------------------------------------------------------
extern "C" void kernel_launch(void* const* d_in, const int* in_sizes, int n_in,
                              void* d_out, int out_size, void* d_ws, size_t ws_size,
                              hipStream_t stream)
{
    const float* x        = (const float*)d_in[0];
    const float* w_disp   = (const float*)d_in[1];
    const float* b_disp   = (const float*)d_in[2];
    const float* w_val    = (const float*)d_in[3];
    const float* b_val    = (const float*)d_in[4];
    const float* rel      = (const float*)d_in[5];
    const float* w_state  = (const float*)d_in[6];
    const float* b_state  = (const float*)d_in[7];
    const float* w_strain = (const float*)d_in[8];
    const float* b_strain = (const float*)d_in[9];
    const float* w_si     = (const float*)d_in[10];
    const float* w_sj     = (const float*)d_in[11];
    const float* w_pos    = (const float*)d_in[12];
    const float* w_bond   = (const float*)d_in[13];
    const float* b_bond   = (const float*)d_in[14];
    const float* w_dmg    = (const float*)d_in[15];
    const float* b_dmg    = (const float*)d_in[16];
    const float* w_dout   = (const float*)d_in[17];
    const float* b_dout   = (const float*)d_in[18];
    const float* w_cproj  = (const float*)d_in[19];
    const float* b_cproj  = (const float*)d_in[20];

    float* out = (float*)d_out;
    float* ws  = (float*)d_ws;

    // fp32 regions (floats): disp[1M] P1[1M] Q1[1M] P2[1M] val[4M]  (= 32 MB)
    const size_t R = (size_t)M_ * 256;
    float* disp = ws;
    float* P1   = ws + R;
    float* Q1   = ws + 2 * R;
    float* P2   = ws + 3 * R;
    float* val  = ws + 4 * R;
    // bf16 regions after 8M floats
    bf16_t* xb   = (bf16_t*)(ws + 8 * R);            // [4096][1024]  8 MB
    bf16_t* attb = xb;                               // alias: xb dead after val GEMM
    bf16_t* wdT  = (bf16_t*)(ws + 10 * R);           // [256][1024]   0.5 MB
    bf16_t* wvT  = wdT + (size_t)256 * 1024;         // [1024][1024]  2 MB
    bf16_t* wcT  = wvT + (size_t)1024 * 1024;        // [1024][1024]  2 MB

    // --- prep: convert x, transpose+convert weights
    convert_bf16_kernel<<<(M_ * C_) / (256 * 8), 256, 0, stream>>>(x, xb, M_ * C_);
    transpose_w_kernel<<<dim3(256 / 32, C_ / 32), 256, 0, stream>>>(w_disp, wdT, C_, 256);
    transpose_w_kernel<<<dim3(C_ / 32, C_ / 32), 256, 0, stream>>>(w_val, wvT, C_, C_);
    transpose_w_kernel<<<dim3(C_ / 32, C_ / 32), 256, 0, stream>>>(w_cproj, wcT, C_, C_);

    // --- disp = x @ w_disp + b_disp  (M x 256)
    gemm_bf16_kernel<<<dim3(256 / BN, M_ / BM), 256, 0, stream>>>(xb, wdT, b_disp, disp, M_, 256, C_);
    // --- val = x @ w_val + b_val     (M x 1024)
    gemm_bf16_kernel<<<dim3(C_ / BN, M_ / BM), 256, 0, stream>>>(xb, wvT, b_val, val, M_, C_, C_);
    // --- state/P1/Q1/P2
    precomp_kernel<<<M_, 256, 0, stream>>>(disp, w_state, b_state, w_strain, b_strain,
                                           w_si, w_sj, w_dmg, P1, Q1, P2);
    // --- attention (writes attb bf16, overwriting xb)
    attn_kernel<<<(B_ * NH_ * T_ / 2) / AW, 256, 0, stream>>>(
        P1, Q1, P2, val, rel, w_pos, w_bond, b_bond, b_dmg, w_dout, b_dout, attb);
    // --- out = att @ w_cproj + b_cproj
    gemm_bf16_kernel<<<dim3(C_ / BN, M_ / BM), 256, 0, stream>>>(attb, wcT, b_cproj, out, M_, C_, C_);
}

// Round 5
// 265.706 us; speedup vs baseline: 40.2543x; 1.1951x over previous
//
#include <hip/hip_runtime.h>
#include <hip/hip_bf16.h>
#include <math.h>

// Problem constants
constexpr int B_ = 2, T_ = 2048, C_ = 1024, NH_ = 16, HS_ = 64, BD_ = 16, DELTA_ = 32;
constexpr int M_ = B_ * T_;   // 4096 rows

typedef __bf16 bf16_t;
typedef __bf16 bf16x8 __attribute__((ext_vector_type(8)));
typedef float  f32x4  __attribute__((ext_vector_type(4)));

// fast gelu: tanh approximation, overflow-safe. |err| vs exact erf-gelu ~1e-3,
// attenuated by w_bond (~0.02) -> logit err ~1e-4, far under threshold.
__device__ __forceinline__ float gelu_f(float x) {
    const float u = 0.7978845608028654f * (x + 0.044715f * x * x * x);
    const float e = __expf(2.0f * u);
    const float th = 1.0f - 2.0f / (e + 1.0f);   // e=inf -> 1, e=0 -> -1
    return 0.5f * x * (1.0f + th);
}

// ---------------------------------------------------------------------------
// convert fp32 -> bf16
// ---------------------------------------------------------------------------
__global__ __launch_bounds__(256) void convert_bf16_kernel(
    const float* __restrict__ in, bf16_t* __restrict__ out, int n)
{
    const int i = (blockIdx.x * 256 + threadIdx.x) * 8;
    if (i >= n) return;
    const float4 v0 = *(const float4*)(in + i);
    const float4 v1 = *(const float4*)(in + i + 4);
    bf16x8 o;
    o[0] = (bf16_t)v0.x; o[1] = (bf16_t)v0.y; o[2] = (bf16_t)v0.z; o[3] = (bf16_t)v0.w;
    o[4] = (bf16_t)v1.x; o[5] = (bf16_t)v1.y; o[6] = (bf16_t)v1.z; o[7] = (bf16_t)v1.w;
    *(bf16x8*)(out + i) = o;
}

// ---------------------------------------------------------------------------
// transpose + convert: in fp32 [K][N] -> out bf16 [N][K]
// ---------------------------------------------------------------------------
__global__ __launch_bounds__(256) void transpose_w_kernel(
    const float* __restrict__ in, bf16_t* __restrict__ out, int K, int N)
{
    __shared__ float tile[32][33];
    const int n0 = blockIdx.x * 32, k0 = blockIdx.y * 32;
    const int tx = threadIdx.x & 31, ty = threadIdx.x >> 5;
    #pragma unroll
    for (int i = 0; i < 4; ++i)
        tile[ty + 8 * i][tx] = in[(size_t)(k0 + ty + 8 * i) * N + n0 + tx];
    __syncthreads();
    #pragma unroll
    for (int i = 0; i < 4; ++i)
        out[(size_t)(n0 + ty + 8 * i) * K + k0 + tx] = (bf16_t)tile[tx][ty + 8 * i];
}

// ---------------------------------------------------------------------------
// bf16 MFMA GEMM with async global->LDS staging (m97 pattern, width=16).
// C[M,N] = A[M,K](bf16 rm) @ Bt[N,K]^T + bias.  Tile 128x64, BK=32, 4 waves.
// ---------------------------------------------------------------------------
__device__ __forceinline__ void gload16(const void* g, void* l) {
    __builtin_amdgcn_global_load_lds(
        (__attribute__((address_space(1))) void*)(g),
        (__attribute__((address_space(3))) void*)(l), 16, 0, 0);
}

#define GBM 128
#define GBN 64
#define GBK 32
__global__ __launch_bounds__(256) void gemm_bf16_async(
    const bf16_t* __restrict__ A, const bf16_t* __restrict__ Bt,
    const float* __restrict__ bias, float* __restrict__ C,
    int M, int N, int K)
{
    __shared__ __align__(16) bf16_t Al[GBM][GBK];   // linear: gload_lds needs base+lane*16
    __shared__ __align__(16) bf16_t Bl[GBN][GBK];
    const int tid  = threadIdx.x;
    const int lane = tid & 63;
    const int w    = tid >> 6;
    const int wr   = w >> 1, wc = w & 1;    // 2x2 waves -> wave tile 64x32
    const int bm   = blockIdx.y * GBM, bn = blockIdx.x * GBN;

    // staging addresses: each wave: 2 A-instrs (16 rows each), 1 B-instr
    const int lrow = lane >> 2;          // 0..15
    const int lcol = (lane & 3) * 8;     // bf16 elems
    const bf16_t* Ag0 = A  + (size_t)(bm + w * 32 + lrow) * K + lcol;
    const bf16_t* Ag1 = Ag0 + (size_t)16 * K;
    const bf16_t* Bg  = Bt + (size_t)(bn + w * 16 + lrow) * K + lcol;

    f32x4 acc[4][2] = {};

    for (int k0 = 0; k0 < K; k0 += GBK) {
        gload16(Ag0 + k0, &Al[w * 32][0]);
        gload16(Ag1 + k0, &Al[w * 32 + 16][0]);
        gload16(Bg  + k0, &Bl[w * 16][0]);
        __syncthreads();   // compiler drains vmcnt before barrier
        bf16x8 af[4], bf2[2];
        #pragma unroll
        for (int i = 0; i < 4; ++i)
            af[i] = *(const bf16x8*)&Al[wr * 64 + i * 16 + (lane & 15)][(lane >> 4) * 8];
        #pragma unroll
        for (int j = 0; j < 2; ++j)
            bf2[j] = *(const bf16x8*)&Bl[wc * 32 + j * 16 + (lane & 15)][(lane >> 4) * 8];
        #pragma unroll
        for (int i = 0; i < 4; ++i)
            #pragma unroll
            for (int j = 0; j < 2; ++j)
                acc[i][j] = __builtin_amdgcn_mfma_f32_16x16x32_bf16(af[i], bf2[j], acc[i][j], 0, 0, 0);
        __syncthreads();   // protect LDS before next stage
    }

    #pragma unroll
    for (int i = 0; i < 4; ++i) {
        const int r0 = bm + wr * 64 + i * 16 + (lane >> 4) * 4;
        #pragma unroll
        for (int j = 0; j < 2; ++j) {
            const int c = bn + wc * 32 + j * 16 + (lane & 15);
            const float bv = bias[c];
            float* cp = C + (size_t)r0 * N + c;
            #pragma unroll
            for (int q = 0; q < 4; ++q)
                cp[(size_t)q * N] = acc[i][j][q] + bv;
        }
    }
}

// ---------------------------------------------------------------------------
// precomp v2: block = (b, h, 128-t tile). Stage disp halo slice in LDS once.
//   mv    = mean_valid(disp window) - disp[t]
//   state = mv @ w_state + b_state
//   P1 = disp@w_strain + state@w_state_j ; Q1 = b_strain + state@w_state_i - disp@w_strain
//   P2 = disp@w_damage
// ---------------------------------------------------------------------------
#define PCT 128
__global__ __launch_bounds__(256) void precomp_kernel(
    const float* __restrict__ disp,
    const float* __restrict__ w_state, const float* __restrict__ b_state,
    const float* __restrict__ w_strain, const float* __restrict__ b_strain,
    const float* __restrict__ w_state_i, const float* __restrict__ w_state_j,
    const float* __restrict__ w_damage,
    float* __restrict__ P1, float* __restrict__ Q1, float* __restrict__ P2)
{
    __shared__ float s_d[PCT + 31][20];    // rows r = t0-31 .. t0+127
    __shared__ float s_mv[PCT][20];
    __shared__ float s_st[PCT][20];
    __shared__ float s_wst[16][16], s_wstr[16][16], s_wsi[16][16], s_wsj[16][16], s_wdmg[16][16];
    __shared__ float s_bst[16], s_bstr[16];

    const int bid = blockIdx.x;            // b*16*(T/PCT) layout
    const int tile = bid & (T_ / PCT - 1);
    const int h    = (bid >> 4) & 15;      // (T_/PCT)=16
    const int b    = bid >> 8;
    const int t0   = tile * PCT;
    const int tid  = threadIdx.x;

    s_wst[tid >> 4][tid & 15]  = w_state[tid];
    s_wstr[tid >> 4][tid & 15] = w_strain[tid];
    s_wsi[tid >> 4][tid & 15]  = w_state_i[tid];
    s_wsj[tid >> 4][tid & 15]  = w_state_j[tid];
    s_wdmg[tid >> 4][tid & 15] = w_damage[tid];
    if (tid < 16) { s_bst[tid] = b_state[tid]; s_bstr[tid] = b_strain[tid]; }

    for (int it = tid; it < (PCT + 31) * 4; it += 256) {
        const int row = it >> 2, q = it & 3;
        int rg = t0 - 31 + row; if (rg < 0) rg = 0;
        *(float4*)&s_d[row][q * 4] =
            *(const float4*)(disp + (size_t)(b * T_ + rg) * 256 + h * 16 + q * 4);
    }
    __syncthreads();

    #pragma unroll
    for (int p = 0; p < 8; ++p) {
        const int it = p * 256 + tid;
        const int tl = it >> 4, e = it & 15;
        const int t = t0 + tl;
        const int dlo = max(0, 31 - t);
        float s = 0.0f;
        for (int d = dlo; d < 32; ++d) s += s_d[tl + d][e];
        s_mv[tl][e] = s / (float)(32 - dlo) - s_d[tl + 31][e];
    }
    __syncthreads();

    #pragma unroll
    for (int p = 0; p < 8; ++p) {
        const int it = p * 256 + tid;
        const int tl = it >> 4, e = it & 15;
        float a = s_bst[e];
        #pragma unroll
        for (int k = 0; k < 16; ++k) a += s_mv[tl][k] * s_wst[k][e];
        s_st[tl][e] = a;
    }
    __syncthreads();

    #pragma unroll
    for (int p = 0; p < 8; ++p) {
        const int it = p * 256 + tid;
        const int tl = it >> 4, e = it & 15;
        float d1 = 0.0f, p2 = 0.0f, sj = 0.0f, si = 0.0f;
        #pragma unroll
        for (int k = 0; k < 16; ++k) {
            const float dv = s_d[tl + 31][k];
            const float sv = s_st[tl][k];
            d1 += dv * s_wstr[k][e];
            p2 += dv * s_wdmg[k][e];
            sj += sv * s_wsj[k][e];
            si += sv * s_wsi[k][e];
        }
        const size_t o = (size_t)(b * T_ + t0 + tl) * 256 + h * 16 + e;
        P1[o] = d1 + sj;
        Q1[o] = s_bstr[e] + si - d1;
        P2[o] = p2;
    }
}

// ---------------------------------------------------------------------------
// attn v3: block = (b, h, 64-t tile). Stage P1/P2 (95 halo rows), Q1 (64 rows),
// val slice (95 x 64 fp32) in LDS. Wave w scores t-pairs 8w..8w+7 (lane = half,d),
// softmax in-wave, wv -> LDS, banded PV from LDS. No barrier between scoring
// and PV (wave reads only its own sWv rows).
// ---------------------------------------------------------------------------
__global__ __launch_bounds__(256) void attn_kernel(
    const float* __restrict__ P1, const float* __restrict__ Q1,
    const float* __restrict__ P2, const float* __restrict__ val,
    const float* __restrict__ rel_pos_emb, const float* __restrict__ w_pos,
    const float* __restrict__ w_bond_out, const float* __restrict__ b_bond_out,
    const float* __restrict__ b_damage,
    const float* __restrict__ w_damage_out, const float* __restrict__ b_damage_out,
    bf16_t* __restrict__ att)
{
    __shared__ float sP1[95][20], sP2[95][20], sQ1[64][20];
    __shared__ float sVal[95][68];          // stride 68: 16B aligned, 2 lanes/bank on PV
    __shared__ float sWv[64][33];
    __shared__ float s_relw[32][20];
    __shared__ float s_wb[16], s_wd[16], s_bd[16];

    const int tid  = threadIdx.x;
    const int bid  = blockIdx.x;
    const int tile = bid & 31;              // T/64 = 32
    const int h    = (bid >> 5) & 15;
    const int b    = bid >> 9;
    const int t0   = tile * 64;

    // ---- stage ----
    for (int it = tid; it < 95 * 4; it += 256) {
        const int row = it >> 2, q = it & 3;
        int rg = t0 - 31 + row; if (rg < 0) rg = 0;
        const size_t o = (size_t)(b * T_ + rg) * 256 + h * 16 + q * 4;
        *(float4*)&sP1[row][q * 4] = *(const float4*)(P1 + o);
        *(float4*)&sP2[row][q * 4] = *(const float4*)(P2 + o);
    }
    {
        const int row = tid >> 2, q = tid & 3;
        *(float4*)&sQ1[row][q * 4] =
            *(const float4*)(Q1 + (size_t)(b * T_ + t0 + row) * 256 + h * 16 + q * 4);
    }
    for (int it = tid; it < 95 * 16; it += 256) {
        const int row = it >> 4, q = it & 15;
        int rg = t0 - 31 + row; if (rg < 0) rg = 0;
        *(float4*)&sVal[row][q * 4] =
            *(const float4*)(val + (size_t)(b * T_ + rg) * 1024 + h * 64 + q * 4);
    }
    {   // relw[d][e] = rel_emb[d] @ w_pos
        for (int it = tid; it < 512; it += 256) {
            const int dd = it >> 4, ee = it & 15;
            float a = 0.0f;
            #pragma unroll
            for (int k = 0; k < 16; ++k) a += rel_pos_emb[dd * 16 + k] * w_pos[k * 16 + ee];
            s_relw[dd][ee] = a;
        }
        if (tid < 16) {
            s_wb[tid] = w_bond_out[tid];
            s_wd[tid] = w_damage_out[tid];
            s_bd[tid] = b_damage[tid];
        }
    }
    __syncthreads();

    const int lane = tid & 63;
    const int w    = tid >> 6;
    const int half = lane >> 5;
    const int d    = lane & 31;
    const float bb  = b_bond_out[0];
    const float bdo = b_damage_out[0];

    // ---- scoring: wave w handles pairs p = 8w..8w+7 (t_local 16w..16w+15) ----
    #pragma unroll
    for (int pp = 0; pp < 8; ++pp) {
        const int p  = (w << 3) + pp;
        const int tl = (p << 1) + half;     // t_local
        const int i  = tl + d;              // LDS row of r = t-31+d
        const bool valid = (t0 - 31 + i) >= 0;

        float bacc = 0.0f, dacc = 0.0f;
        #pragma unroll
        for (int q = 0; q < 4; ++q) {
            const float4 q1  = *(const float4*)&sQ1[tl][q * 4];
            const float4 p2t = *(const float4*)&sP2[tl + 31][q * 4];
            const float4 p1r = *(const float4*)&sP1[i][q * 4];
            const float4 p2r = *(const float4*)&sP2[i][q * 4];
            const float4 rw  = *(const float4*)&s_relw[d][q * 4];
            bacc += gelu_f(p1r.x + q1.x + rw.x) * s_wb[4 * q + 0];
            bacc += gelu_f(p1r.y + q1.y + rw.y) * s_wb[4 * q + 1];
            bacc += gelu_f(p1r.z + q1.z + rw.z) * s_wb[4 * q + 2];
            bacc += gelu_f(p1r.w + q1.w + rw.w) * s_wb[4 * q + 3];
            dacc += gelu_f(p2r.x - p2t.x + s_bd[4 * q + 0]) * s_wd[4 * q + 0];
            dacc += gelu_f(p2r.y - p2t.y + s_bd[4 * q + 1]) * s_wd[4 * q + 1];
            dacc += gelu_f(p2r.z - p2t.z + s_bd[4 * q + 2]) * s_wd[4 * q + 2];
            dacc += gelu_f(p2r.w - p2t.w + s_bd[4 * q + 3]) * s_wd[4 * q + 3];
        }

        float logit = -INFINITY;
        if (valid) {
            const float damage = 1.0f / (1.0f + __expf(-(dacc + bdo)));
            logit = bacc + bb - 10.0f * damage;
        }
        float m = logit;
        #pragma unroll
        for (int off = 16; off; off >>= 1) m = fmaxf(m, __shfl_xor(m, off, 32));
        const float pe = valid ? __expf(logit - m) : 0.0f;
        float ss = pe;
        #pragma unroll
        for (int off = 16; off; off >>= 1) ss += __shfl_xor(ss, off, 32);
        sWv[tl][d] = pe / ss;
    }

    // ---- PV: wave w, lane = e, t_local 16w..16w+15 as 8 merged pairs ----
    #pragma unroll
    for (int pp = 0; pp < 8; ++pp) {
        const int tl0 = (w << 4) + (pp << 1);
        float acc0 = 0.0f, acc1 = 0.0f;
        #pragma unroll
        for (int j = 0; j < 33; ++j) {
            const float v = sVal[tl0 + j][lane];
            if (j < 32) acc0 += sWv[tl0][j] * v;
            if (j >= 1) acc1 += sWv[tl0 + 1][j - 1] * v;
        }
        const size_t o = (size_t)(b * T_ + t0 + tl0) * 1024 + h * 64 + lane;
        att[o]        = (bf16_t)acc0;
        att[o + 1024] = (bf16_t)acc1;
    }
}

// ---------------------------------------------------------------------------
extern "C" void kernel_launch(void* const* d_in, const int* in_sizes, int n_in,
                              void* d_out, int out_size, void* d_ws, size_t ws_size,
                              hipStream_t stream)
{
    const float* x        = (const float*)d_in[0];
    const float* w_disp   = (const float*)d_in[1];
    const float* b_disp   = (const float*)d_in[2];
    const float* w_val    = (const float*)d_in[3];
    const float* b_val    = (const float*)d_in[4];
    const float* rel      = (const float*)d_in[5];
    const float* w_state  = (const float*)d_in[6];
    const float* b_state  = (const float*)d_in[7];
    const float* w_strain = (const float*)d_in[8];
    const float* b_strain = (const float*)d_in[9];
    const float* w_si     = (const float*)d_in[10];
    const float* w_sj     = (const float*)d_in[11];
    const float* w_pos    = (const float*)d_in[12];
    const float* w_bond   = (const float*)d_in[13];
    const float* b_bond   = (const float*)d_in[14];
    const float* w_dmg    = (const float*)d_in[15];
    const float* b_dmg    = (const float*)d_in[16];
    const float* w_dout   = (const float*)d_in[17];
    const float* b_dout   = (const float*)d_in[18];
    const float* w_cproj  = (const float*)d_in[19];
    const float* b_cproj  = (const float*)d_in[20];

    float* out = (float*)d_out;
    float* ws  = (float*)d_ws;

    // fp32 regions (floats): disp[1M] P1[1M] Q1[1M] P2[1M] val[4M]  (= 32 MB)
    const size_t R = (size_t)M_ * 256;
    float* disp = ws;
    float* P1   = ws + R;
    float* Q1   = ws + 2 * R;
    float* P2   = ws + 3 * R;
    float* val  = ws + 4 * R;
    // bf16 regions after 8M floats
    bf16_t* xb   = (bf16_t*)(ws + 8 * R);            // [4096][1024]  8 MB
    bf16_t* attb = xb;                               // alias: xb dead after val GEMM
    bf16_t* wdT  = (bf16_t*)(ws + 10 * R);           // [256][1024]
    bf16_t* wvT  = wdT + (size_t)256 * 1024;         // [1024][1024]
    bf16_t* wcT  = wvT + (size_t)1024 * 1024;        // [1024][1024]

    convert_bf16_kernel<<<(M_ * C_) / (256 * 8), 256, 0, stream>>>(x, xb, M_ * C_);
    transpose_w_kernel<<<dim3(256 / 32, C_ / 32), 256, 0, stream>>>(w_disp, wdT, C_, 256);
    transpose_w_kernel<<<dim3(C_ / 32, C_ / 32), 256, 0, stream>>>(w_val, wvT, C_, C_);
    transpose_w_kernel<<<dim3(C_ / 32, C_ / 32), 256, 0, stream>>>(w_cproj, wcT, C_, C_);

    gemm_bf16_async<<<dim3(256 / GBN, M_ / GBM), 256, 0, stream>>>(xb, wdT, b_disp, disp, M_, 256, C_);
    gemm_bf16_async<<<dim3(C_ / GBN, M_ / GBM), 256, 0, stream>>>(xb, wvT, b_val, val, M_, C_, C_);

    precomp_kernel<<<B_ * NH_ * (T_ / PCT), 256, 0, stream>>>(
        disp, w_state, b_state, w_strain, b_strain, w_si, w_sj, w_dmg, P1, Q1, P2);

    attn_kernel<<<B_ * NH_ * (T_ / 64), 256, 0, stream>>>(
        P1, Q1, P2, val, rel, w_pos, w_bond, b_bond, b_dmg, w_dout, b_dout, attb);

    gemm_bf16_async<<<dim3(C_ / GBN, M_ / GBM), 256, 0, stream>>>(attb, wcT, b_cproj, out, M_, C_, C_);
}

// Round 8
// 224.341 us; speedup vs baseline: 47.6765x; 1.1844x over previous
//
#include <hip/hip_runtime.h>
#include <hip/hip_bf16.h>
#include <math.h>

// Problem constants
constexpr int B_ = 2, T_ = 2048, C_ = 1024, NH_ = 16, HS_ = 64, BD_ = 16, DELTA_ = 32;
constexpr int M_ = B_ * T_;   // 4096 rows

typedef __bf16 bf16_t;
typedef __bf16 bf16x8 __attribute__((ext_vector_type(8)));
typedef float  f32x4  __attribute__((ext_vector_type(4)));

__device__ __forceinline__ float frcp(float x)  { return __builtin_amdgcn_rcpf(x); }
__device__ __forceinline__ float fexp2(float x) { return __builtin_amdgcn_exp2f(x); }

// tanh-gelu, division-free:  gelu(x) = x - x * rcp(exp2(c1*x + c2*x^3) + 1)
// c1 = 2*log2(e)*0.7978845608 = 2.3022074, c2 = c1*0.044715 = 0.10294321
__device__ __forceinline__ float gelu_f(float x) {
    const float x2  = x * x;
    const float arg = x * fmaf(0.10294321f, x2, 2.3022074f);
    const float e   = fexp2(arg);
    const float r   = frcp(e + 1.0f);
    return x - x * r;
}
constexpr float LOG2E = 1.4426950409f;

// ---------------------------------------------------------------------------
// convert fp32 -> bf16
// ---------------------------------------------------------------------------
__global__ __launch_bounds__(256) void convert_bf16_kernel(
    const float* __restrict__ in, bf16_t* __restrict__ out, int n)
{
    const int i = (blockIdx.x * 256 + threadIdx.x) * 8;
    if (i >= n) return;
    const float4 v0 = *(const float4*)(in + i);
    const float4 v1 = *(const float4*)(in + i + 4);
    bf16x8 o;
    o[0] = (bf16_t)v0.x; o[1] = (bf16_t)v0.y; o[2] = (bf16_t)v0.z; o[3] = (bf16_t)v0.w;
    o[4] = (bf16_t)v1.x; o[5] = (bf16_t)v1.y; o[6] = (bf16_t)v1.z; o[7] = (bf16_t)v1.w;
    *(bf16x8*)(out + i) = o;
}

// ---------------------------------------------------------------------------
// fused transpose+convert of the three weight matrices (z selects matrix)
// ---------------------------------------------------------------------------
__global__ __launch_bounds__(256) void transpose3_kernel(
    const float* __restrict__ w_val, const float* __restrict__ w_cproj,
    const float* __restrict__ w_disp,
    bf16_t* __restrict__ wvT, bf16_t* __restrict__ wcT, bf16_t* __restrict__ wdT)
{
    const int z = blockIdx.z;
    const float* in; bf16_t* out; int K = 1024, N = 1024;
    if (z == 0)      { in = w_val;   out = wvT; }
    else if (z == 1) { in = w_cproj; out = wcT; }
    else             { in = w_disp;  out = wdT; N = 256; if (blockIdx.x >= 8) return; }

    __shared__ float tile[32][33];
    const int n0 = blockIdx.x * 32, k0 = blockIdx.y * 32;
    const int tx = threadIdx.x & 31, ty = threadIdx.x >> 5;
    #pragma unroll
    for (int i = 0; i < 4; ++i)
        tile[ty + 8 * i][tx] = in[(size_t)(k0 + ty + 8 * i) * N + n0 + tx];
    __syncthreads();
    #pragma unroll
    for (int i = 0; i < 4; ++i)
        out[(size_t)(n0 + ty + 8 * i) * K + k0 + tx] = (bf16_t)tile[tx][ty + 8 * i];
}

// ---------------------------------------------------------------------------
// bf16 MFMA GEMM core, double-buffered global_load_lds staging.
// C[*,N] tile at (bm,bn) = A[*,K] @ Bt[N,K]^T + bias. 128x128 tile, 4 waves.
// ---------------------------------------------------------------------------
__device__ __forceinline__ void gload16(const void* g, void* l) {
    __builtin_amdgcn_global_load_lds(
        (__attribute__((address_space(1))) void*)(g),
        (__attribute__((address_space(3))) void*)(l), 16, 0, 0);
}

#define GBM 128
#define GBN 128
#define GBK 32

__device__ __forceinline__ void gemm_core(
    bf16_t (*Al)[GBM][GBK], bf16_t (*Bl)[GBN][GBK],
    const bf16_t* __restrict__ A, const bf16_t* __restrict__ Bt,
    const float* __restrict__ bias, float* __restrict__ C,
    int N, int K, int bm, int bn)
{
    const int tid  = threadIdx.x;
    const int lane = tid & 63;
    const int w    = tid >> 6;
    const int wr   = w >> 1, wc = w & 1;       // 2x2 waves, wave tile 64x64

    const int lrow = lane >> 2;          // 0..15
    const int lcol = (lane & 3) * 8;     // bf16 elems
    const bf16_t* Ag0 = A  + (size_t)(bm + w * 32 + lrow) * K + lcol;
    const bf16_t* Ag1 = Ag0 + (size_t)16 * K;
    const bf16_t* Bg0 = Bt + (size_t)(bn + w * 32 + lrow) * K + lcol;
    const bf16_t* Bg1 = Bg0 + (size_t)16 * K;

    f32x4 acc[4][4] = {};
    const int nt = K / GBK;
    int cur = 0;

    gload16(Ag0, &Al[0][w * 32][0]);
    gload16(Ag1, &Al[0][w * 32 + 16][0]);
    gload16(Bg0, &Bl[0][w * 32][0]);
    gload16(Bg1, &Bl[0][w * 32 + 16][0]);
    __syncthreads();

    for (int t = 0; t < nt; ++t) {
        if (t + 1 < nt) {   // prefetch next tile into other buffer
            const int k1 = (t + 1) * GBK;
            gload16(Ag0 + k1, &Al[cur ^ 1][w * 32][0]);
            gload16(Ag1 + k1, &Al[cur ^ 1][w * 32 + 16][0]);
            gload16(Bg0 + k1, &Bl[cur ^ 1][w * 32][0]);
            gload16(Bg1 + k1, &Bl[cur ^ 1][w * 32 + 16][0]);
        }
        bf16x8 af[4], bfr[4];
        #pragma unroll
        for (int i = 0; i < 4; ++i)
            af[i] = *(const bf16x8*)&Al[cur][wr * 64 + i * 16 + (lane & 15)][(lane >> 4) * 8];
        #pragma unroll
        for (int j = 0; j < 4; ++j)
            bfr[j] = *(const bf16x8*)&Bl[cur][wc * 64 + j * 16 + (lane & 15)][(lane >> 4) * 8];
        #pragma unroll
        for (int i = 0; i < 4; ++i)
            #pragma unroll
            for (int j = 0; j < 4; ++j)
                acc[i][j] = __builtin_amdgcn_mfma_f32_16x16x32_bf16(af[i], bfr[j], acc[i][j], 0, 0, 0);
        __syncthreads();   // drains vmcnt (next tile resident) + protects LDS
        cur ^= 1;
    }

    #pragma unroll
    for (int i = 0; i < 4; ++i) {
        const int r0 = bm + wr * 64 + i * 16 + (lane >> 4) * 4;
        #pragma unroll
        for (int j = 0; j < 4; ++j) {
            const int c = bn + wc * 64 + j * 16 + (lane & 15);
            const float bv = bias[c];
            float* cp = C + (size_t)r0 * N + c;
            #pragma unroll
            for (int q = 0; q < 4; ++q)
                cp[(size_t)q * N] = acc[i][j][q] + bv;
        }
    }
}

// generic GEMM (used for cproj): grid (N/128, M/128), XCD-chunked swizzle
__global__ __launch_bounds__(256) void gemm_bf16_db(
    const bf16_t* __restrict__ A, const bf16_t* __restrict__ Bt,
    const float* __restrict__ bias, float* __restrict__ C,
    int M, int N, int K)
{
    __shared__ __align__(16) bf16_t Al[2][GBM][GBK];
    __shared__ __align__(16) bf16_t Bl[2][GBN][GBK];
    const int gx  = gridDim.x;
    const int nwg = gx * gridDim.y;
    const int bid = blockIdx.y * gx + blockIdx.x;
    const int wid = (bid & 7) * (nwg >> 3) + (bid >> 3);   // nwg % 8 == 0
    const int bx  = wid % gx, by = wid / gx;
    gemm_core(Al, Bl, A, Bt, bias, C, N, K, by * GBM, bx * GBN);
}

// fused val+disp GEMM: grid (10, 32). bx<8 -> val (N=1024), bx>=8 -> disp (N=256)
__global__ __launch_bounds__(256) void gemm_dv_fused(
    const bf16_t* __restrict__ A,
    const bf16_t* __restrict__ wvT, const bf16_t* __restrict__ wdT,
    const float* __restrict__ b_val, const float* __restrict__ b_disp,
    float* __restrict__ val, float* __restrict__ disp)
{
    __shared__ __align__(16) bf16_t Al[2][GBM][GBK];
    __shared__ __align__(16) bf16_t Bl[2][GBN][GBK];
    const int gx  = 10;
    const int nwg = 320;
    const int bid = blockIdx.y * gx + blockIdx.x;
    const int wid = (bid & 7) * (nwg >> 3) + (bid >> 3);   // 320 % 8 == 0, bijective
    const int bx  = wid % gx, by = wid / gx;
    if (bx < 8)
        gemm_core(Al, Bl, A, wvT, b_val, val, 1024, 1024, by * GBM, bx * GBN);
    else
        gemm_core(Al, Bl, A, wdT, b_disp, disp, 256, 1024, by * GBM, (bx - 8) * GBN);
}

// ---------------------------------------------------------------------------
// precomp: block = (b, h, 128-t tile). Stage disp halo slice in LDS once.
// ---------------------------------------------------------------------------
#define PCT 128
__global__ __launch_bounds__(256) void precomp_kernel(
    const float* __restrict__ disp,
    const float* __restrict__ w_state, const float* __restrict__ b_state,
    const float* __restrict__ w_strain, const float* __restrict__ b_strain,
    const float* __restrict__ w_state_i, const float* __restrict__ w_state_j,
    const float* __restrict__ w_damage,
    float* __restrict__ P1, float* __restrict__ Q1, float* __restrict__ P2)
{
    __shared__ float s_d[PCT + 31][20];
    __shared__ float s_mv[PCT][20];
    __shared__ float s_st[PCT][20];
    __shared__ float s_wst[16][16], s_wstr[16][16], s_wsi[16][16], s_wsj[16][16], s_wdmg[16][16];
    __shared__ float s_bst[16], s_bstr[16];

    const int bid = blockIdx.x;
    const int tile = bid & (T_ / PCT - 1);
    const int h    = (bid >> 4) & 15;
    const int b    = bid >> 8;
    const int t0   = tile * PCT;
    const int tid  = threadIdx.x;

    s_wst[tid >> 4][tid & 15]  = w_state[tid];
    s_wstr[tid >> 4][tid & 15] = w_strain[tid];
    s_wsi[tid >> 4][tid & 15]  = w_state_i[tid];
    s_wsj[tid >> 4][tid & 15]  = w_state_j[tid];
    s_wdmg[tid >> 4][tid & 15] = w_damage[tid];
    if (tid < 16) { s_bst[tid] = b_state[tid]; s_bstr[tid] = b_strain[tid]; }

    for (int it = tid; it < (PCT + 31) * 4; it += 256) {
        const int row = it >> 2, q = it & 3;
        int rg = t0 - 31 + row; if (rg < 0) rg = 0;
        *(float4*)&s_d[row][q * 4] =
            *(const float4*)(disp + (size_t)(b * T_ + rg) * 256 + h * 16 + q * 4);
    }
    __syncthreads();

    #pragma unroll
    for (int p = 0; p < 8; ++p) {
        const int it = p * 256 + tid;
        const int tl = it >> 4, e = it & 15;
        const int t = t0 + tl;
        const int dlo = max(0, 31 - t);
        float s = 0.0f;
        for (int d = dlo; d < 32; ++d) s += s_d[tl + d][e];
        s_mv[tl][e] = s * frcp((float)(32 - dlo)) - s_d[tl + 31][e];
    }
    __syncthreads();

    #pragma unroll
    for (int p = 0; p < 8; ++p) {
        const int it = p * 256 + tid;
        const int tl = it >> 4, e = it & 15;
        float a = s_bst[e];
        #pragma unroll
        for (int k = 0; k < 16; ++k) a += s_mv[tl][k] * s_wst[k][e];
        s_st[tl][e] = a;
    }
    __syncthreads();

    #pragma unroll
    for (int p = 0; p < 8; ++p) {
        const int it = p * 256 + tid;
        const int tl = it >> 4, e = it & 15;
        float d1 = 0.0f, p2 = 0.0f, sj = 0.0f, si = 0.0f;
        #pragma unroll
        for (int k = 0; k < 16; ++k) {
            const float dv = s_d[tl + 31][k];
            const float sv = s_st[tl][k];
            d1 += dv * s_wstr[k][e];
            p2 += dv * s_wdmg[k][e];
            sj += sv * s_wsj[k][e];
            si += sv * s_wsi[k][e];
        }
        const size_t o = (size_t)(b * T_ + t0 + tl) * 256 + h * 16 + e;
        P1[o] = d1 + sj;
        Q1[o] = s_bstr[e] + si - d1;
        P2[o] = p2;
    }
}

// ---------------------------------------------------------------------------
// attn: block = (b, h, 64-t tile). Stage P1/P2 (95 halo rows), Q1, val slice
// in LDS. Wave w scores t-pairs, softmax in-wave, wv -> LDS, banded PV.
// All transcendentals via exp2/rcp (no IEEE division).
// ---------------------------------------------------------------------------
__global__ __launch_bounds__(256) void attn_kernel(
    const float* __restrict__ P1, const float* __restrict__ Q1,
    const float* __restrict__ P2, const float* __restrict__ val,
    const float* __restrict__ rel_pos_emb, const float* __restrict__ w_pos,
    const float* __restrict__ w_bond_out, const float* __restrict__ b_bond_out,
    const float* __restrict__ b_damage,
    const float* __restrict__ w_damage_out, const float* __restrict__ b_damage_out,
    bf16_t* __restrict__ att)
{
    __shared__ float sP1[95][20], sP2[95][20], sQ1[64][20];
    __shared__ float sVal[95][68];
    __shared__ float sWv[64][33];
    __shared__ float s_relw[32][20];
    __shared__ float s_wb[16], s_wd[16], s_bd[16];

    const int tid  = threadIdx.x;
    const int bid  = blockIdx.x;
    const int tile = bid & 31;
    const int h    = (bid >> 5) & 15;
    const int b    = bid >> 9;
    const int t0   = tile * 64;

    for (int it = tid; it < 95 * 4; it += 256) {
        const int row = it >> 2, q = it & 3;
        int rg = t0 - 31 + row; if (rg < 0) rg = 0;
        const size_t o = (size_t)(b * T_ + rg) * 256 + h * 16 + q * 4;
        *(float4*)&sP1[row][q * 4] = *(const float4*)(P1 + o);
        *(float4*)&sP2[row][q * 4] = *(const float4*)(P2 + o);
    }
    {
        const int row = tid >> 2, q = tid & 3;
        *(float4*)&sQ1[row][q * 4] =
            *(const float4*)(Q1 + (size_t)(b * T_ + t0 + row) * 256 + h * 16 + q * 4);
    }
    for (int it = tid; it < 95 * 16; it += 256) {
        const int row = it >> 4, q = it & 15;
        int rg = t0 - 31 + row; if (rg < 0) rg = 0;
        *(float4*)&sVal[row][q * 4] =
            *(const float4*)(val + (size_t)(b * T_ + rg) * 1024 + h * 64 + q * 4);
    }
    {
        for (int it = tid; it < 512; it += 256) {
            const int dd = it >> 4, ee = it & 15;
            float a = 0.0f;
            #pragma unroll
            for (int k = 0; k < 16; ++k) a += rel_pos_emb[dd * 16 + k] * w_pos[k * 16 + ee];
            s_relw[dd][ee] = a;
        }
        if (tid < 16) {
            s_wb[tid] = w_bond_out[tid];
            s_wd[tid] = w_damage_out[tid];
            s_bd[tid] = b_damage[tid];
        }
    }
    __syncthreads();

    const int lane = tid & 63;
    const int w    = tid >> 6;
    const int half = lane >> 5;
    const int d    = lane & 31;
    const float bb  = b_bond_out[0];
    const float bdo = b_damage_out[0];

    #pragma unroll
    for (int pp = 0; pp < 8; ++pp) {
        const int p  = (w << 3) + pp;
        const int tl = (p << 1) + half;
        const int i  = tl + d;
        const bool valid = (t0 - 31 + i) >= 0;

        float bacc = 0.0f, dacc = 0.0f;
        #pragma unroll
        for (int q = 0; q < 4; ++q) {
            const float4 q1  = *(const float4*)&sQ1[tl][q * 4];
            const float4 p2t = *(const float4*)&sP2[tl + 31][q * 4];
            const float4 p1r = *(const float4*)&sP1[i][q * 4];
            const float4 p2r = *(const float4*)&sP2[i][q * 4];
            const float4 rw  = *(const float4*)&s_relw[d][q * 4];
            bacc += gelu_f(p1r.x + q1.x + rw.x) * s_wb[4 * q + 0];
            bacc += gelu_f(p1r.y + q1.y + rw.y) * s_wb[4 * q + 1];
            bacc += gelu_f(p1r.z + q1.z + rw.z) * s_wb[4 * q + 2];
            bacc += gelu_f(p1r.w + q1.w + rw.w) * s_wb[4 * q + 3];
            dacc += gelu_f(p2r.x - p2t.x + s_bd[4 * q + 0]) * s_wd[4 * q + 0];
            dacc += gelu_f(p2r.y - p2t.y + s_bd[4 * q + 1]) * s_wd[4 * q + 1];
            dacc += gelu_f(p2r.z - p2t.z + s_bd[4 * q + 2]) * s_wd[4 * q + 2];
            dacc += gelu_f(p2r.w - p2t.w + s_bd[4 * q + 3]) * s_wd[4 * q + 3];
        }

        float logit = -INFINITY;
        if (valid) {
            const float damage = frcp(1.0f + fexp2(-LOG2E * (dacc + bdo)));
            logit = bacc + bb - 10.0f * damage;
        }
        float m = logit;
        #pragma unroll
        for (int off = 16; off; off >>= 1) m = fmaxf(m, __shfl_xor(m, off, 32));
        const float pe = valid ? fexp2(LOG2E * (logit - m)) : 0.0f;
        float ss = pe;
        #pragma unroll
        for (int off = 16; off; off >>= 1) ss += __shfl_xor(ss, off, 32);
        sWv[tl][d] = pe * frcp(ss);
    }

    #pragma unroll
    for (int pp = 0; pp < 8; ++pp) {
        const int tl0 = (w << 4) + (pp << 1);
        float acc0 = 0.0f, acc1 = 0.0f;
        #pragma unroll
        for (int j = 0; j < 33; ++j) {
            const float v = sVal[tl0 + j][lane];
            if (j < 32) acc0 += sWv[tl0][j] * v;
            if (j >= 1) acc1 += sWv[tl0 + 1][j - 1] * v;
        }
        const size_t o = (size_t)(b * T_ + t0 + tl0) * 1024 + h * 64 + lane;
        att[o]        = (bf16_t)acc0;
        att[o + 1024] = (bf16_t)acc1;
    }
}

// ---------------------------------------------------------------------------
extern "C" void kernel_launch(void* const* d_in, const int* in_sizes, int n_in,
                              void* d_out, int out_size, void* d_ws, size_t ws_size,
                              hipStream_t stream)
{
    const float* x        = (const float*)d_in[0];
    const float* w_disp   = (const float*)d_in[1];
    const float* b_disp   = (const float*)d_in[2];
    const float* w_val    = (const float*)d_in[3];
    const float* b_val    = (const float*)d_in[4];
    const float* rel      = (const float*)d_in[5];
    const float* w_state  = (const float*)d_in[6];
    const float* b_state  = (const float*)d_in[7];
    const float* w_strain = (const float*)d_in[8];
    const float* b_strain = (const float*)d_in[9];
    const float* w_si     = (const float*)d_in[10];
    const float* w_sj     = (const float*)d_in[11];
    const float* w_pos    = (const float*)d_in[12];
    const float* w_bond   = (const float*)d_in[13];
    const float* b_bond   = (const float*)d_in[14];
    const float* w_dmg    = (const float*)d_in[15];
    const float* b_dmg    = (const float*)d_in[16];
    const float* w_dout   = (const float*)d_in[17];
    const float* b_dout   = (const float*)d_in[18];
    const float* w_cproj  = (const float*)d_in[19];
    const float* b_cproj  = (const float*)d_in[20];

    float* out = (float*)d_out;
    float* ws  = (float*)d_ws;

    // fp32 regions (floats): disp[1M] P1[1M] Q1[1M] P2[1M] val[4M]  (= 32 MB)
    const size_t R = (size_t)M_ * 256;
    float* disp = ws;
    float* P1   = ws + R;
    float* Q1   = ws + 2 * R;
    float* P2   = ws + 3 * R;
    float* val  = ws + 4 * R;
    // bf16 regions after 8M floats
    bf16_t* xb   = (bf16_t*)(ws + 8 * R);            // [4096][1024]  8 MB
    bf16_t* attb = xb;                               // alias: xb dead after fused GEMM
    bf16_t* wdT  = (bf16_t*)(ws + 10 * R);           // [256][1024]
    bf16_t* wvT  = wdT + (size_t)256 * 1024;         // [1024][1024]
    bf16_t* wcT  = wvT + (size_t)1024 * 1024;        // [1024][1024]

    convert_bf16_kernel<<<(M_ * C_) / (256 * 8), 256, 0, stream>>>(x, xb, M_ * C_);
    transpose3_kernel<<<dim3(32, 32, 3), 256, 0, stream>>>(w_val, w_cproj, w_disp, wvT, wcT, wdT);

    // fused: val = x@w_val + b_val, disp = x@w_disp + b_disp
    gemm_dv_fused<<<dim3(10, 32), 256, 0, stream>>>(xb, wvT, wdT, b_val, b_disp, val, disp);

    precomp_kernel<<<B_ * NH_ * (T_ / PCT), 256, 0, stream>>>(
        disp, w_state, b_state, w_strain, b_strain, w_si, w_sj, w_dmg, P1, Q1, P2);

    attn_kernel<<<B_ * NH_ * (T_ / 64), 256, 0, stream>>>(
        P1, Q1, P2, val, rel, w_pos, w_bond, b_bond, b_dmg, w_dout, b_dout, attb);

    gemm_bf16_db<<<dim3(C_ / GBN, M_ / GBM), 256, 0, stream>>>(attb, wcT, b_cproj, out, M_, C_, C_);
}

// Round 9
// 215.421 us; speedup vs baseline: 49.6507x; 1.0414x over previous
//
#include <hip/hip_runtime.h>
#include <hip/hip_bf16.h>
#include <math.h>

// Problem constants
constexpr int B_ = 2, T_ = 2048, C_ = 1024, NH_ = 16, HS_ = 64, BD_ = 16, DELTA_ = 32;
constexpr int M_ = B_ * T_;   // 4096 rows

typedef __bf16 bf16_t;
typedef __bf16 bf16x8 __attribute__((ext_vector_type(8)));
typedef float  f32x4  __attribute__((ext_vector_type(4)));

__device__ __forceinline__ float frcp(float x)  { return __builtin_amdgcn_rcpf(x); }
__device__ __forceinline__ float fexp2(float x) { return __builtin_amdgcn_exp2f(x); }
__device__ __forceinline__ float rlane(float v, int l) {
    return __builtin_bit_cast(float, __builtin_amdgcn_readlane(__builtin_bit_cast(int, v), l));
}

// tanh-gelu, division-free:  gelu(x) = x - x * rcp(exp2(c1*x + c2*x^3) + 1)
__device__ __forceinline__ float gelu_f(float x) {
    const float x2  = x * x;
    const float arg = x * fmaf(0.10294321f, x2, 2.3022074f);
    const float e   = fexp2(arg);
    const float r   = frcp(e + 1.0f);
    return x - x * r;
}
constexpr float LOG2E = 1.4426950409f;

// ---------------------------------------------------------------------------
// convert fp32 -> bf16
// ---------------------------------------------------------------------------
__global__ __launch_bounds__(256) void convert_bf16_kernel(
    const float* __restrict__ in, bf16_t* __restrict__ out, int n)
{
    const int i = (blockIdx.x * 256 + threadIdx.x) * 8;
    if (i >= n) return;
    const float4 v0 = *(const float4*)(in + i);
    const float4 v1 = *(const float4*)(in + i + 4);
    bf16x8 o;
    o[0] = (bf16_t)v0.x; o[1] = (bf16_t)v0.y; o[2] = (bf16_t)v0.z; o[3] = (bf16_t)v0.w;
    o[4] = (bf16_t)v1.x; o[5] = (bf16_t)v1.y; o[6] = (bf16_t)v1.z; o[7] = (bf16_t)v1.w;
    *(bf16x8*)(out + i) = o;
}

// ---------------------------------------------------------------------------
// fused transpose+convert of the three weight matrices (z selects matrix)
// ---------------------------------------------------------------------------
__global__ __launch_bounds__(256) void transpose3_kernel(
    const float* __restrict__ w_val, const float* __restrict__ w_cproj,
    const float* __restrict__ w_disp,
    bf16_t* __restrict__ wvT, bf16_t* __restrict__ wcT, bf16_t* __restrict__ wdT)
{
    const int z = blockIdx.z;
    const float* in; bf16_t* out; int K = 1024, N = 1024;
    if (z == 0)      { in = w_val;   out = wvT; }
    else if (z == 1) { in = w_cproj; out = wcT; }
    else             { in = w_disp;  out = wdT; N = 256; if (blockIdx.x >= 8) return; }

    __shared__ float tile[32][33];
    const int n0 = blockIdx.x * 32, k0 = blockIdx.y * 32;
    const int tx = threadIdx.x & 31, ty = threadIdx.x >> 5;
    #pragma unroll
    for (int i = 0; i < 4; ++i)
        tile[ty + 8 * i][tx] = in[(size_t)(k0 + ty + 8 * i) * N + n0 + tx];
    __syncthreads();
    #pragma unroll
    for (int i = 0; i < 4; ++i)
        out[(size_t)(n0 + ty + 8 * i) * K + k0 + tx] = (bf16_t)tile[tx][ty + 8 * i];
}

// ---------------------------------------------------------------------------
// bf16 MFMA GEMM core, 128x64 tile, double-buffered global_load_lds staging.
// Small tile -> 512-640 block grids -> 2+ blocks/CU co-residency (hides the
// per-K-step barrier drain via wave-level overlap, m114 mechanism).
// ---------------------------------------------------------------------------
__device__ __forceinline__ void gload16(const void* g, void* l) {
    __builtin_amdgcn_global_load_lds(
        (__attribute__((address_space(1))) void*)(g),
        (__attribute__((address_space(3))) void*)(l), 16, 0, 0);
}

#define GBM 128
#define GBN 64
#define GBK 32

__device__ __forceinline__ void gemm_core(
    bf16_t (*Al)[GBM][GBK], bf16_t (*Bl)[GBN][GBK],
    const bf16_t* __restrict__ A, const bf16_t* __restrict__ Bt,
    const float* __restrict__ bias, float* __restrict__ C,
    int N, int K, int bm, int bn)
{
    const int tid  = threadIdx.x;
    const int lane = tid & 63;
    const int w    = tid >> 6;
    const int wr   = w >> 1, wc = w & 1;       // 2x2 waves, wave tile 64x32

    const int lrow = lane >> 2;          // 0..15
    const int lcol = (lane & 3) * 8;     // bf16 elems
    const bf16_t* Ag0 = A  + (size_t)(bm + w * 32 + lrow) * K + lcol;
    const bf16_t* Ag1 = Ag0 + (size_t)16 * K;
    const bf16_t* Bg  = Bt + (size_t)(bn + w * 16 + lrow) * K + lcol;

    f32x4 acc[4][2] = {};
    const int nt = K / GBK;
    int cur = 0;

    gload16(Ag0, &Al[0][w * 32][0]);
    gload16(Ag1, &Al[0][w * 32 + 16][0]);
    gload16(Bg,  &Bl[0][w * 16][0]);
    __syncthreads();

    for (int t = 0; t < nt; ++t) {
        if (t + 1 < nt) {   // prefetch next K-tile into the other buffer
            const int k1 = (t + 1) * GBK;
            gload16(Ag0 + k1, &Al[cur ^ 1][w * 32][0]);
            gload16(Ag1 + k1, &Al[cur ^ 1][w * 32 + 16][0]);
            gload16(Bg  + k1, &Bl[cur ^ 1][w * 16][0]);
        }
        bf16x8 af[4], bfr[2];
        #pragma unroll
        for (int i = 0; i < 4; ++i)
            af[i] = *(const bf16x8*)&Al[cur][wr * 64 + i * 16 + (lane & 15)][(lane >> 4) * 8];
        #pragma unroll
        for (int j = 0; j < 2; ++j)
            bfr[j] = *(const bf16x8*)&Bl[cur][wc * 32 + j * 16 + (lane & 15)][(lane >> 4) * 8];
        #pragma unroll
        for (int i = 0; i < 4; ++i)
            #pragma unroll
            for (int j = 0; j < 2; ++j)
                acc[i][j] = __builtin_amdgcn_mfma_f32_16x16x32_bf16(af[i], bfr[j], acc[i][j], 0, 0, 0);
        __syncthreads();   // drains vmcnt (next tile resident) + protects LDS
        cur ^= 1;
    }

    #pragma unroll
    for (int i = 0; i < 4; ++i) {
        const int r0 = bm + wr * 64 + i * 16 + (lane >> 4) * 4;
        #pragma unroll
        for (int j = 0; j < 2; ++j) {
            const int c = bn + wc * 32 + j * 16 + (lane & 15);
            const float bv = bias[c];
            float* cp = C + (size_t)r0 * N + c;
            #pragma unroll
            for (int q = 0; q < 4; ++q)
                cp[(size_t)q * N] = acc[i][j][q] + bv;
        }
    }
}

// generic GEMM (cproj): grid (N/64, M/128), XCD-chunked swizzle
__global__ __launch_bounds__(256) void gemm_bf16_db(
    const bf16_t* __restrict__ A, const bf16_t* __restrict__ Bt,
    const float* __restrict__ bias, float* __restrict__ C,
    int M, int N, int K)
{
    __shared__ __align__(16) bf16_t Al[2][GBM][GBK];
    __shared__ __align__(16) bf16_t Bl[2][GBN][GBK];
    const int gx  = gridDim.x;
    const int nwg = gx * gridDim.y;
    const int bid = blockIdx.y * gx + blockIdx.x;
    const int wid = (bid & 7) * (nwg >> 3) + (bid >> 3);   // nwg % 8 == 0
    const int bx  = wid % gx, by = wid / gx;
    gemm_core(Al, Bl, A, Bt, bias, C, N, K, by * GBM, bx * GBN);
}

// fused val+disp GEMM: grid (20, 32). bx<16 -> val (N=1024), bx>=16 -> disp (N=256)
__global__ __launch_bounds__(256) void gemm_dv_fused(
    const bf16_t* __restrict__ A,
    const bf16_t* __restrict__ wvT, const bf16_t* __restrict__ wdT,
    const float* __restrict__ b_val, const float* __restrict__ b_disp,
    float* __restrict__ val, float* __restrict__ disp)
{
    __shared__ __align__(16) bf16_t Al[2][GBM][GBK];
    __shared__ __align__(16) bf16_t Bl[2][GBN][GBK];
    const int gx  = 20;
    const int nwg = 640;
    const int bid = blockIdx.y * gx + blockIdx.x;
    const int wid = (bid & 7) * (nwg >> 3) + (bid >> 3);   // 640 % 8 == 0, bijective
    const int bx  = wid % gx, by = wid / gx;
    if (bx < 16)
        gemm_core(Al, Bl, A, wvT, b_val, val, 1024, 1024, by * GBM, bx * GBN);
    else
        gemm_core(Al, Bl, A, wdT, b_disp, disp, 256, 1024, by * GBM, (bx - 16) * GBN);
}

// ---------------------------------------------------------------------------
// precomp: block = (b, h, 128-t tile). Stage disp halo slice in LDS once.
// ---------------------------------------------------------------------------
#define PCT 128
__global__ __launch_bounds__(256) void precomp_kernel(
    const float* __restrict__ disp,
    const float* __restrict__ w_state, const float* __restrict__ b_state,
    const float* __restrict__ w_strain, const float* __restrict__ b_strain,
    const float* __restrict__ w_state_i, const float* __restrict__ w_state_j,
    const float* __restrict__ w_damage,
    float* __restrict__ P1, float* __restrict__ Q1, float* __restrict__ P2)
{
    __shared__ float s_d[PCT + 31][20];
    __shared__ float s_mv[PCT][20];
    __shared__ float s_st[PCT][20];
    __shared__ float s_wst[16][16], s_wstr[16][16], s_wsi[16][16], s_wsj[16][16], s_wdmg[16][16];
    __shared__ float s_bst[16], s_bstr[16];

    const int bid = blockIdx.x;
    const int tile = bid & (T_ / PCT - 1);
    const int h    = (bid >> 4) & 15;
    const int b    = bid >> 8;
    const int t0   = tile * PCT;
    const int tid  = threadIdx.x;

    s_wst[tid >> 4][tid & 15]  = w_state[tid];
    s_wstr[tid >> 4][tid & 15] = w_strain[tid];
    s_wsi[tid >> 4][tid & 15]  = w_state_i[tid];
    s_wsj[tid >> 4][tid & 15]  = w_state_j[tid];
    s_wdmg[tid >> 4][tid & 15] = w_damage[tid];
    if (tid < 16) { s_bst[tid] = b_state[tid]; s_bstr[tid] = b_strain[tid]; }

    for (int it = tid; it < (PCT + 31) * 4; it += 256) {
        const int row = it >> 2, q = it & 3;
        int rg = t0 - 31 + row; if (rg < 0) rg = 0;
        *(float4*)&s_d[row][q * 4] =
            *(const float4*)(disp + (size_t)(b * T_ + rg) * 256 + h * 16 + q * 4);
    }
    __syncthreads();

    #pragma unroll
    for (int p = 0; p < 8; ++p) {
        const int it = p * 256 + tid;
        const int tl = it >> 4, e = it & 15;
        const int t = t0 + tl;
        const int dlo = max(0, 31 - t);
        float s = 0.0f;
        for (int d = dlo; d < 32; ++d) s += s_d[tl + d][e];
        s_mv[tl][e] = s * frcp((float)(32 - dlo)) - s_d[tl + 31][e];
    }
    __syncthreads();

    #pragma unroll
    for (int p = 0; p < 8; ++p) {
        const int it = p * 256 + tid;
        const int tl = it >> 4, e = it & 15;
        float a = s_bst[e];
        #pragma unroll
        for (int k = 0; k < 16; ++k) a += s_mv[tl][k] * s_wst[k][e];
        s_st[tl][e] = a;
    }
    __syncthreads();

    #pragma unroll
    for (int p = 0; p < 8; ++p) {
        const int it = p * 256 + tid;
        const int tl = it >> 4, e = it & 15;
        float d1 = 0.0f, p2 = 0.0f, sj = 0.0f, si = 0.0f;
        #pragma unroll
        for (int k = 0; k < 16; ++k) {
            const float dv = s_d[tl + 31][k];
            const float sv = s_st[tl][k];
            d1 += dv * s_wstr[k][e];
            p2 += dv * s_wdmg[k][e];
            sj += sv * s_wsj[k][e];
            si += sv * s_wsi[k][e];
        }
        const size_t o = (size_t)(b * T_ + t0 + tl) * 256 + h * 16 + e;
        P1[o] = d1 + sj;
        Q1[o] = s_bstr[e] + si - d1;
        P2[o] = p2;
    }
}

// ---------------------------------------------------------------------------
// attn v4: block = (b, h, 64-t tile).
//  LDS: sP1/sP2 (95 halo rows), sQ1, sVal as bf16 (~36.7 KB -> 4 blocks/CU).
//  Softmax weights stay in registers (wv[8], static idx); PV broadcasts them
//  via v_readlane (compile-time lane) -- no sWv buffer, no extra barrier.
// ---------------------------------------------------------------------------
__global__ __launch_bounds__(256, 4) void attn_kernel(
    const float* __restrict__ P1, const float* __restrict__ Q1,
    const float* __restrict__ P2, const float* __restrict__ val,
    const float* __restrict__ rel_pos_emb, const float* __restrict__ w_pos,
    const float* __restrict__ w_bond_out, const float* __restrict__ b_bond_out,
    const float* __restrict__ b_damage,
    const float* __restrict__ w_damage_out, const float* __restrict__ b_damage_out,
    bf16_t* __restrict__ att)
{
    __shared__ float  sP1[95][20], sP2[95][20], sQ1[64][20];
    __shared__ bf16_t sVal[95][72];          // bf16; col reads 2 lanes/bank (free)
    __shared__ float  s_relw[32][20];
    __shared__ float  s_wb[16], s_wd[16], s_bd[16];

    const int tid  = threadIdx.x;
    const int bid  = blockIdx.x;
    const int tile = bid & 31;
    const int h    = (bid >> 5) & 15;
    const int b    = bid >> 9;
    const int t0   = tile * 64;

    for (int it = tid; it < 95 * 4; it += 256) {
        const int row = it >> 2, q = it & 3;
        int rg = t0 - 31 + row; if (rg < 0) rg = 0;
        const size_t o = (size_t)(b * T_ + rg) * 256 + h * 16 + q * 4;
        *(float4*)&sP1[row][q * 4] = *(const float4*)(P1 + o);
        *(float4*)&sP2[row][q * 4] = *(const float4*)(P2 + o);
    }
    {
        const int row = tid >> 2, q = tid & 3;
        *(float4*)&sQ1[row][q * 4] =
            *(const float4*)(Q1 + (size_t)(b * T_ + t0 + row) * 256 + h * 16 + q * 4);
    }
    // stage val slice as bf16: 95 rows x 64 e, 8 e's per chunk
    for (int it = tid; it < 95 * 8; it += 256) {
        const int row = it >> 3, c8 = (it & 7) * 8;
        int rg = t0 - 31 + row; if (rg < 0) rg = 0;
        const float* vp = val + (size_t)(b * T_ + rg) * 1024 + h * 64 + c8;
        const float4 va = *(const float4*)(vp);
        const float4 vb = *(const float4*)(vp + 4);
        bf16x8 o;
        o[0] = (bf16_t)va.x; o[1] = (bf16_t)va.y; o[2] = (bf16_t)va.z; o[3] = (bf16_t)va.w;
        o[4] = (bf16_t)vb.x; o[5] = (bf16_t)vb.y; o[6] = (bf16_t)vb.z; o[7] = (bf16_t)vb.w;
        *(bf16x8*)&sVal[row][c8] = o;
    }
    {
        for (int it = tid; it < 512; it += 256) {
            const int dd = it >> 4, ee = it & 15;
            float a = 0.0f;
            #pragma unroll
            for (int k = 0; k < 16; ++k) a += rel_pos_emb[dd * 16 + k] * w_pos[k * 16 + ee];
            s_relw[dd][ee] = a;
        }
        if (tid < 16) {
            s_wb[tid] = w_bond_out[tid];
            s_wd[tid] = w_damage_out[tid];
            s_bd[tid] = b_damage[tid];
        }
    }
    __syncthreads();

    const int lane = tid & 63;
    const int w    = tid >> 6;
    const int half = lane >> 5;
    const int d    = lane & 31;
    const float bb  = b_bond_out[0];
    const float bdo = b_damage_out[0];

    float wv[8];

    // ---- scoring: wave w handles pairs 8w..8w+7 (t_local 16w..16w+15) ----
    #pragma unroll
    for (int pp = 0; pp < 8; ++pp) {
        const int p  = (w << 3) + pp;
        const int tl = (p << 1) + half;
        const int i  = tl + d;
        const bool valid = (t0 - 31 + i) >= 0;

        float bacc = 0.0f, dacc = 0.0f;
        #pragma unroll
        for (int q = 0; q < 4; ++q) {
            const float4 q1  = *(const float4*)&sQ1[tl][q * 4];
            const float4 p2t = *(const float4*)&sP2[tl + 31][q * 4];
            const float4 p1r = *(const float4*)&sP1[i][q * 4];
            const float4 p2r = *(const float4*)&sP2[i][q * 4];
            const float4 rw  = *(const float4*)&s_relw[d][q * 4];
            bacc += gelu_f(p1r.x + q1.x + rw.x) * s_wb[4 * q + 0];
            bacc += gelu_f(p1r.y + q1.y + rw.y) * s_wb[4 * q + 1];
            bacc += gelu_f(p1r.z + q1.z + rw.z) * s_wb[4 * q + 2];
            bacc += gelu_f(p1r.w + q1.w + rw.w) * s_wb[4 * q + 3];
            dacc += gelu_f(p2r.x - p2t.x + s_bd[4 * q + 0]) * s_wd[4 * q + 0];
            dacc += gelu_f(p2r.y - p2t.y + s_bd[4 * q + 1]) * s_wd[4 * q + 1];
            dacc += gelu_f(p2r.z - p2t.z + s_bd[4 * q + 2]) * s_wd[4 * q + 2];
            dacc += gelu_f(p2r.w - p2t.w + s_bd[4 * q + 3]) * s_wd[4 * q + 3];
        }

        float logit = -INFINITY;
        if (valid) {
            const float damage = frcp(1.0f + fexp2(-LOG2E * (dacc + bdo)));
            logit = bacc + bb - 10.0f * damage;
        }
        float m = logit;
        #pragma unroll
        for (int off = 16; off; off >>= 1) m = fmaxf(m, __shfl_xor(m, off, 32));
        const float pe = valid ? fexp2(LOG2E * (logit - m)) : 0.0f;
        float ss = pe;
        #pragma unroll
        for (int off = 16; off; off >>= 1) ss += __shfl_xor(ss, off, 32);
        wv[pp] = pe * frcp(ss);
    }

    // ---- PV: wave w, lane = e; weights broadcast via readlane ----
    #pragma unroll
    for (int pp = 0; pp < 8; ++pp) {
        const int tl0 = (w << 4) + (pp << 1);
        float acc0 = 0.0f, acc1 = 0.0f;
        #pragma unroll
        for (int j = 0; j < 33; ++j) {
            const float v = (float)sVal[tl0 + j][lane];
            if (j < 32) acc0 += rlane(wv[pp], j) * v;        // t0+tl0,  d=j   (lanes 0..31)
            if (j >= 1) acc1 += rlane(wv[pp], 31 + j) * v;   // t0+tl0+1,d=j-1 (lanes 32..63)
        }
        const size_t o = (size_t)(b * T_ + t0 + tl0) * 1024 + h * 64 + lane;
        att[o]        = (bf16_t)acc0;
        att[o + 1024] = (bf16_t)acc1;
    }
}

// ---------------------------------------------------------------------------
extern "C" void kernel_launch(void* const* d_in, const int* in_sizes, int n_in,
                              void* d_out, int out_size, void* d_ws, size_t ws_size,
                              hipStream_t stream)
{
    const float* x        = (const float*)d_in[0];
    const float* w_disp   = (const float*)d_in[1];
    const float* b_disp   = (const float*)d_in[2];
    const float* w_val    = (const float*)d_in[3];
    const float* b_val    = (const float*)d_in[4];
    const float* rel      = (const float*)d_in[5];
    const float* w_state  = (const float*)d_in[6];
    const float* b_state  = (const float*)d_in[7];
    const float* w_strain = (const float*)d_in[8];
    const float* b_strain = (const float*)d_in[9];
    const float* w_si     = (const float*)d_in[10];
    const float* w_sj     = (const float*)d_in[11];
    const float* w_pos    = (const float*)d_in[12];
    const float* w_bond   = (const float*)d_in[13];
    const float* b_bond   = (const float*)d_in[14];
    const float* w_dmg    = (const float*)d_in[15];
    const float* b_dmg    = (const float*)d_in[16];
    const float* w_dout   = (const float*)d_in[17];
    const float* b_dout   = (const float*)d_in[18];
    const float* w_cproj  = (const float*)d_in[19];
    const float* b_cproj  = (const float*)d_in[20];

    float* out = (float*)d_out;
    float* ws  = (float*)d_ws;

    // fp32 regions (floats): disp[1M] P1[1M] Q1[1M] P2[1M] val[4M]  (= 32 MB)
    const size_t R = (size_t)M_ * 256;
    float* disp = ws;
    float* P1   = ws + R;
    float* Q1   = ws + 2 * R;
    float* P2   = ws + 3 * R;
    float* val  = ws + 4 * R;
    // bf16 regions after 8M floats
    bf16_t* xb   = (bf16_t*)(ws + 8 * R);            // [4096][1024]  8 MB
    bf16_t* attb = xb;                               // alias: xb dead after fused GEMM
    bf16_t* wdT  = (bf16_t*)(ws + 10 * R);           // [256][1024]
    bf16_t* wvT  = wdT + (size_t)256 * 1024;         // [1024][1024]
    bf16_t* wcT  = wvT + (size_t)1024 * 1024;        // [1024][1024]

    convert_bf16_kernel<<<(M_ * C_) / (256 * 8), 256, 0, stream>>>(x, xb, M_ * C_);
    transpose3_kernel<<<dim3(32, 32, 3), 256, 0, stream>>>(w_val, w_cproj, w_disp, wvT, wcT, wdT);

    // fused: val = x@w_val + b_val, disp = x@w_disp + b_disp  (640 blocks)
    gemm_dv_fused<<<dim3(20, 32), 256, 0, stream>>>(xb, wvT, wdT, b_val, b_disp, val, disp);

    precomp_kernel<<<B_ * NH_ * (T_ / PCT), 256, 0, stream>>>(
        disp, w_state, b_state, w_strain, b_strain, w_si, w_sj, w_dmg, P1, Q1, P2);

    attn_kernel<<<B_ * NH_ * (T_ / 64), 256, 0, stream>>>(
        P1, Q1, P2, val, rel, w_pos, w_bond, b_bond, b_dmg, w_dout, b_dout, attb);

    // out = att @ w_cproj + b_cproj  (512 blocks)
    gemm_bf16_db<<<dim3(C_ / GBN, M_ / GBM), 256, 0, stream>>>(attb, wcT, b_cproj, out, M_, C_, C_);
}